// Round 8
// baseline (266.369 us; speedup 1.0000x reference)
//
#include <hip/hip_runtime.h>
#include <hip/hip_bf16.h>
#include <math.h>

// ---------------- problem constants ----------------
#define LHALF   20          // L = M//2, M = 41
#define HDIM    175         // number of (m,n) index pairs, verified below
#define BATCH   65536
#define SLOPE   0.01f

#define BPB     64          // batch elems per block (= lanes per wave)
#define BLOCK   256         // 4 waves; compile-time h-split across waves
#define XROW    520         // bytes per i-row in LDS: 64 quads * 8B + 8B pad

// ---------------- compile-time index tables ----------------
constexpr int count_idx() {
    int k = 0;
    for (int m = -LHALF; m <= LHALF; ++m)
        for (int n = m; n <= LHALF; ++n) {
            int mn = m * n; if (mn < 0) mn = -mn;
            int s  = m + n; if (s  < 0) s  = -s;
            if (mn <= LHALF && s <= LHALF) ++k;
        }
    return k;
}
static_assert(count_idx() == HDIM, "HDIM mismatch with reference enumeration");

struct OffTab { int n[HDIM]; int mn[HDIM]; int m[HDIM]; unsigned char sym2[HDIM]; };

constexpr OffTab make_offtab() {
    OffTab t{};
    int k = 0;
    for (int m = -LHALF; m <= LHALF; ++m)
        for (int n = m; n <= LHALF; ++n) {
            int mn = m * n; if (mn < 0) mn = -mn;
            int s  = m + n; if (s  < 0) s  = -s;
            if (mn <= LHALF && s <= LHALF) {
                t.n[k]    = (LHALF + n)     * XROW;   // byte offsets, compile-time
                t.mn[k]   = (LHALF + m + n) * XROW;
                t.m[k]    = (LHALF + m)     * XROW;
                t.sym2[k] = (m != n) ? 1 : 0;
                ++k;
            }
        }
    return t;
}

constexpr OffTab KOFF = make_offtab();     // folded into immediates in unrolled code

// runtime copy of sym for the pk-build phase (indexed by runtime t)
__constant__ unsigned char g_sym2[HDIM] = {};  // replaced below via constexpr init

struct SymArr { unsigned char v[HDIM]; };
constexpr SymArr make_sym() {
    SymArr s{};
    OffTab t = make_offtab();
    for (int i = 0; i < HDIM; ++i) s.v[i] = t.sym2[i];
    return s;
}
__constant__ SymArr g_sym = make_sym();

__device__ __forceinline__ float lrelu(float v) {
    return v > 0.0f ? v : SLOPE * v;
}

// bf16 quad (re0,im0,re1,im1) -> 4 floats
__device__ __forceinline__ float4 dec(uint2 q) {
    float4 r;
    r.x = __uint_as_float(q.x << 16);
    r.y = __uint_as_float(q.x & 0xffff0000u);
    r.z = __uint_as_float(q.y << 16);
    r.w = __uint_as_float(q.y & 0xffff0000u);
    return r;
}

// f32 -> bf16 (round-to-nearest-even)
__device__ __forceinline__ unsigned short f2bf(float f) {
    unsigned int u = __float_as_uint(f);
    u += 0x7fffu + ((u >> 16) & 1u);
    return (unsigned short)(u >> 16);
}

// ---- fully-unrolled h-loop with compile-time immediate LDS offsets ----
template<int H0, int H1>
__device__ __forceinline__ void hloop(const char* __restrict__ xlane,
                                      const float4* __restrict__ pk4,
                                      float* __restrict__ a)
{
    #pragma unroll
    for (int h = H0; h < H1; ++h) {
        // W1' row (sym pre-folded): 2 broadcast b128 reads at immediate offsets
        float4 wA = pk4[2 * h];
        float4 wB = pk4[2 * h + 1];
        // x quads at compile-time immediate offsets -> independent ds_read_b64
        float4 En  = dec(*reinterpret_cast<const uint2*>(xlane + KOFF.n[h]));
        float4 Emn = dec(*reinterpret_cast<const uint2*>(xlane + KOFF.mn[h]));
        float4 Em  = dec(*reinterpret_cast<const uint2*>(xlane + KOFF.m[h]));

        // A = sum over modes of En * conj(Emn)
        float ar = En.x * Emn.x + En.y * Emn.y + En.z * Emn.z + En.w * Emn.w;
        float ai = En.y * Emn.x - En.x * Emn.y + En.w * Emn.z - En.z * Emn.w;

        // F[p] = A * Em[p]
        float fr0 = ar * Em.x - ai * Em.y, fi0 = ar * Em.y + ai * Em.x;
        float fr1 = ar * Em.z - ai * Em.w, fi1 = ar * Em.w + ai * Em.z;

        // acc[p][o] += F[p] * W1'[p][o][h]
        a[0] += fr0 * wA.x - fi0 * wA.y;  a[1] += fr0 * wA.y + fi0 * wA.x;
        a[2] += fr0 * wA.z - fi0 * wA.w;  a[3] += fr0 * wA.w + fi0 * wA.z;
        a[4] += fr1 * wB.x - fi1 * wB.y;  a[5] += fr1 * wB.y + fi1 * wB.x;
        a[6] += fr1 * wB.z - fi1 * wB.w;  a[7] += fr1 * wB.w + fi1 * wB.z;
    }
}

// ---------------- kernel ----------------
__global__ __launch_bounds__(BLOCK, 4) void eqpbcnn_kernel(
    const float* __restrict__ x_real, const float* __restrict__ x_imag,
    const float* __restrict__ task,
    const float* __restrict__ W1r, const float* __restrict__ W1i,
    const float* __restrict__ W2r, const float* __restrict__ W2i,
    const float* __restrict__ W3r, const float* __restrict__ W3i,
    float* __restrict__ out)
{
    __shared__ __align__(16) char   xsb[41 * XROW];    // 21.3 KB bf16 quads
    __shared__ __align__(16) float4 pk4[HDIM * 2];     // 5.6 KB  W1'*sym, 32 B/h
    __shared__ float mrg[4][8][BPB];                   // 8 KB    per-wave partials
    __shared__ float2 w2s[2 * 10 * 2];
    __shared__ float2 w3s[2 * 10];

    const int t  = threadIdx.x;
    const int b0 = blockIdx.x * BPB;
    const int ln = t & 63;
    const int wv = t >> 6;          // wave id 0..3

    // ---- stage x: flat coalesced float2 loads; bf16 quad writes ----
    {
        const float2* xr2 = reinterpret_cast<const float2*>(x_real) + (size_t)b0 * 41;
        const float2* xi2 = reinterpret_cast<const float2*>(x_imag) + (size_t)b0 * 41;
        for (int f = t; f < BPB * 41; f += BLOCK) {
            float2 r2 = xr2[f];
            float2 i2 = xi2[f];
            int bl = f / 41;            // magic div
            int i  = f - bl * 41;
            ushort4 q;
            q.x = f2bf(r2.x); q.y = f2bf(i2.x);
            q.z = f2bf(r2.y); q.w = f2bf(i2.y);
            *reinterpret_cast<ushort4*>(xsb + i * XROW + bl * 8) = q;
        }
    }
    // ---- build pk: W1 * sym, 8 floats per h (no offsets needed anymore) ----
    if (t < HDIM) {
        float sym = g_sym.v[t] ? 2.0f : 1.0f;
        float4 wA, wB;
        wA.x = W1r[0 * HDIM + t] * sym;  wA.y = W1i[0 * HDIM + t] * sym;
        wA.z = W1r[1 * HDIM + t] * sym;  wA.w = W1i[1 * HDIM + t] * sym;
        wB.x = W1r[2 * HDIM + t] * sym;  wB.y = W1i[2 * HDIM + t] * sym;
        wB.z = W1r[3 * HDIM + t] * sym;  wB.w = W1i[3 * HDIM + t] * sym;
        pk4[2 * t]     = wA;
        pk4[2 * t + 1] = wB;
    }
    if (t >= 192 && t < 192 + 40)
        w2s[t - 192] = make_float2(W2r[t - 192], W2i[t - 192]);
    if (t >= 232 && t < 232 + 20)
        w3s[t - 232] = make_float2(W3r[t - 232], W3i[t - 232]);
    __syncthreads();

    // ---- h-loop: compile-time h-range per wave, fully unrolled ----
    float a[8] = {0.f, 0.f, 0.f, 0.f, 0.f, 0.f, 0.f, 0.f};
    const char* xlane = xsb + ln * 8;

    if      (wv == 0) hloop<  0,  44>(xlane, pk4, a);
    else if (wv == 1) hloop< 44,  88>(xlane, pk4, a);
    else if (wv == 2) hloop< 88, 132>(xlane, pk4, a);
    else              hloop<132, HDIM>(xlane, pk4, a);

    // ---- store per-wave partials ----
    #pragma unroll
    for (int k = 0; k < 8; ++k)
        mrg[wv][k][ln] = a[k];
    __syncthreads();

    // ---- parallel merge: thread t owns (k = t>>6, lane = t&63) ----
    {
        int k = t >> 6;
        #pragma unroll
        for (int kk = 0; kk < 2; ++kk) {       // 8 k-slots / 4 thread-groups
            int ks = k * 2 + kk;
            float s = mrg[0][ks][ln] + mrg[1][ks][ln]
                    + mrg[2][ks][ln] + mrg[3][ks][ln];
            mrg[0][ks][ln] = s;
        }
    }
    __syncthreads();

    // ---- MLP tail: one thread per batch elem ----
    if (t < BPB) {
        float h1r[2][2], h1i[2][2];
        #pragma unroll
        for (int p = 0; p < 2; ++p)
            #pragma unroll
            for (int o = 0; o < 2; ++o) {
                h1r[p][o] = lrelu(mrg[0][(p * 2 + o) * 2 + 0][t]);
                h1i[p][o] = lrelu(mrg[0][(p * 2 + o) * 2 + 1][t]);
            }

        float Er[2], Ei[2];
        #pragma unroll
        for (int p = 0; p < 2; ++p) {
            float er = 0.f, ei = 0.f;
            #pragma unroll
            for (int q = 0; q < 10; ++q) {
                float hr = 0.f, hi = 0.f;
                #pragma unroll
                for (int o = 0; o < 2; ++o) {
                    float2 w = w2s[(p * 10 + q) * 2 + o];
                    hr += h1r[p][o] * w.x - h1i[p][o] * w.y;
                    hi += h1r[p][o] * w.y + h1i[p][o] * w.x;
                }
                hr = lrelu(hr); hi = lrelu(hi);
                float2 w3 = w3s[p * 10 + q];
                er += hr * w3.x - hi * w3.y;
                ei += hr * w3.y + hi * w3.x;
            }
            Er[p] = er; Ei[p] = ei;
        }

        int gb = b0 + t;
        float P = exp10f(task[gb * 4] * 0.1f) * 0.5f;   // 10^(ti/10) / NMODES

        // exact fp32 x[:,L,:] re-read from global (carrier term exact)
        const float* xrL = x_real + (size_t)gb * 82 + LHALF * 2;
        const float* xiL = x_imag + (size_t)gb * 82 + LHALF * 2;

        float4 o4;
        o4.x = xrL[0] + Er[0] * P;
        o4.y = xiL[0] + Ei[0] * P;
        o4.z = xrL[1] + Er[1] * P;
        o4.w = xiL[1] + Ei[1] * P;
        reinterpret_cast<float4*>(out)[gb] = o4;
    }
}

// ---------------- launch ----------------
extern "C" void kernel_launch(void* const* d_in, const int* in_sizes, int n_in,
                              void* d_out, int out_size, void* d_ws, size_t ws_size,
                              hipStream_t stream) {
    const float* x_real = (const float*)d_in[0];
    const float* x_imag = (const float*)d_in[1];
    const float* task   = (const float*)d_in[2];
    const float* W1r    = (const float*)d_in[3];
    const float* W1i    = (const float*)d_in[4];
    const float* W2r    = (const float*)d_in[5];
    const float* W2i    = (const float*)d_in[6];
    const float* W3r    = (const float*)d_in[7];
    const float* W3i    = (const float*)d_in[8];
    float* out = (float*)d_out;

    dim3 grid(BATCH / BPB);
    dim3 block(BLOCK);
    hipLaunchKernelGGL(eqpbcnn_kernel, grid, block, 0, stream,
                       x_real, x_imag, task, W1r, W1i, W2r, W2i, W3r, W3i, out);
}

// Round 9
// 34.460 us; speedup vs baseline: 7.7298x; 7.7298x over previous
//
#include <hip/hip_runtime.h>
#include <hip/hip_bf16.h>
#include <math.h>

// ---------------- problem constants ----------------
#define LHALF   20          // L = M//2, M = 41
#define HDIM    175         // number of (m,n) index pairs, verified below
#define BATCH   65536
#define SLOPE   0.01f

#define BPB     64          // batch elems per block (= lanes per wave)
#define BLOCK   256         // 4 waves; waves split the h-range at runtime
#define NWAVE   4
#define XROW    520         // bytes per i-row in LDS: 64 quads * 8B + 8B pad

// ---------------- compile-time layout ----------------
// Entries ordered m-major then n; for fixed m the admissible n-range is
// CONTIGUOUS (intersection of intervals), so the h-loop walks (m-group, n).
constexpr int count_idx() {
    int k = 0;
    for (int m = -LHALF; m <= LHALF; ++m)
        for (int n = m; n <= LHALF; ++n) {
            int mn = m * n; if (mn < 0) mn = -mn;
            int s  = m + n; if (s  < 0) s  = -s;
            if (mn <= LHALF && s <= LHALF) ++k;
        }
    return k;
}
static_assert(count_idx() == HDIM, "HDIM mismatch with reference enumeration");

struct Layout {
    int n0[42]; int n1[42];          // per mi (m = mi-20); n1<n0 => empty group
    int mi0[NWAVE]; int nf[NWAVE];   // per wave: starting group + starting n
    unsigned char sym2[HDIM];        // 1 if m != n
};

constexpr Layout make_layout() {
    Layout t{};
    for (int i = 0; i < 42; ++i) { t.n0[i] = 1; t.n1[i] = 0; }
    constexpr int hstart[NWAVE] = {0, 44, 88, 132};
    int h = 0;
    for (int m = -LHALF; m <= LHALF; ++m) {
        bool first = true;
        for (int n = m; n <= LHALF; ++n) {
            int mn = m * n; if (mn < 0) mn = -mn;
            int s  = m + n; if (s  < 0) s  = -s;
            if (mn <= LHALF && s <= LHALF) {
                int mi = m + LHALF;
                if (first) { t.n0[mi] = n; first = false; }
                t.n1[mi] = n;
                t.sym2[h] = (m != n) ? 1 : 0;
                for (int w = 0; w < NWAVE; ++w)
                    if (h == hstart[w]) { t.mi0[w] = mi; t.nf[w] = n; }
                ++h;
            }
        }
    }
    return t;
}

__constant__ Layout g_lay = make_layout();

__device__ __forceinline__ float lrelu(float v) {
    return v > 0.0f ? v : SLOPE * v;
}

// bf16 quad (re0,im0,re1,im1) -> 4 floats
__device__ __forceinline__ float4 dec(uint2 q) {
    float4 r;
    r.x = __uint_as_float(q.x << 16);
    r.y = __uint_as_float(q.x & 0xffff0000u);
    r.z = __uint_as_float(q.y << 16);
    r.w = __uint_as_float(q.y & 0xffff0000u);
    return r;
}
__device__ __forceinline__ float bf_lo(unsigned int u) { return __uint_as_float(u << 16); }
__device__ __forceinline__ float bf_hi(unsigned int u) { return __uint_as_float(u & 0xffff0000u); }

// f32 -> bf16 (round-to-nearest-even)
__device__ __forceinline__ unsigned short f2bf(float f) {
    unsigned int u = __float_as_uint(f);
    u += 0x7fffu + ((u >> 16) & 1u);
    return (unsigned short)(u >> 16);
}
__device__ __forceinline__ unsigned int pack2(float a, float b) {
    return (unsigned int)f2bf(a) | ((unsigned int)f2bf(b) << 16);
}

// ---------------- kernel ----------------
__global__ __launch_bounds__(BLOCK, 4) void eqpbcnn_kernel(
    const float* __restrict__ x_real, const float* __restrict__ x_imag,
    const float* __restrict__ task,
    const float* __restrict__ W1r, const float* __restrict__ W1i,
    const float* __restrict__ W2r, const float* __restrict__ W2i,
    const float* __restrict__ W3r, const float* __restrict__ W3i,
    float* __restrict__ out)
{
    __shared__ __align__(16) char  xsb[41 * XROW];     // 21.3 KB bf16 x quads; merge aliases after h-loop
    __shared__ __align__(16) uint4 pk4[HDIM];          // 2.8 KB  W1'*sym in bf16x8
    __shared__ float2 w2s[2 * 10 * 2];
    __shared__ float2 w3s[2 * 10];

    const int t  = threadIdx.x;
    const int b0 = blockIdx.x * BPB;
    const int ln = t & 63;
    const int wv = t >> 6;          // wave id 0..3

    // ---- stage x: flat coalesced float2 loads; bf16 quad writes ----
    {
        const float2* xr2 = reinterpret_cast<const float2*>(x_real) + (size_t)b0 * 41;
        const float2* xi2 = reinterpret_cast<const float2*>(x_imag) + (size_t)b0 * 41;
        for (int f = t; f < BPB * 41; f += BLOCK) {
            float2 r2 = xr2[f];
            float2 i2 = xi2[f];
            int bl = f / 41;            // magic div
            int i  = f - bl * 41;
            ushort4 q;
            q.x = f2bf(r2.x); q.y = f2bf(i2.x);
            q.z = f2bf(r2.y); q.w = f2bf(i2.y);
            *reinterpret_cast<ushort4*>(xsb + i * XROW + bl * 8) = q;
        }
    }
    // ---- build pk: bf16-packed W1 * sym, 16 B per h ----
    if (t < HDIM) {
        float sym = g_lay.sym2[t] ? 2.0f : 1.0f;
        uint4 w;
        w.x = pack2(W1r[0 * HDIM + t] * sym, W1i[0 * HDIM + t] * sym);  // p0 o0
        w.y = pack2(W1r[1 * HDIM + t] * sym, W1i[1 * HDIM + t] * sym);  // p0 o1
        w.z = pack2(W1r[2 * HDIM + t] * sym, W1i[2 * HDIM + t] * sym);  // p1 o0
        w.w = pack2(W1r[3 * HDIM + t] * sym, W1i[3 * HDIM + t] * sym);  // p1 o1
        pk4[t] = w;
    }
    if (t >= 192 && t < 192 + 40)
        w2s[t - 192] = make_float2(W2r[t - 192], W2i[t - 192]);
    if (t >= 232 && t < 232 + 20)
        w3s[t - 232] = make_float2(W3r[t - 232], W3i[t - 232]);
    __syncthreads();

    // ---- h-loop: m-group walk; Em invariant per group; offsets advance by XROW ----
    float a00r = 0.f, a00i = 0.f, a01r = 0.f, a01i = 0.f;
    float a10r = 0.f, a10i = 0.f, a11r = 0.f, a11i = 0.f;

    const char* xlane = xsb + ln * 8;
    int h          = wv * 44;
    const int hend = (h + 44 < HDIM) ? h + 44 : HDIM;
    int mi = g_lay.mi0[wv];
    int n  = g_lay.nf[wv];

    while (h < hend) {
        int cnt = g_lay.n1[mi] - n + 1;
        int rem = hend - h;
        if (cnt > rem) cnt = rem;
        if (cnt > 0) {
            float4 Em = dec(*reinterpret_cast<const uint2*>(xlane + mi * XROW));
            const char* pn  = xlane + (LHALF + n) * XROW;
            const char* pmn = xlane + (mi + n) * XROW;
            #pragma unroll 2
            for (int c = 0; c < cnt; ++c) {
                uint4 w = pk4[h + c];                       // broadcast b128
                float4 En  = dec(*reinterpret_cast<const uint2*>(pn  + c * XROW));
                float4 Emn = dec(*reinterpret_cast<const uint2*>(pmn + c * XROW));

                // A = sum over modes of En * conj(Emn)
                float ar = En.x * Emn.x + En.y * Emn.y + En.z * Emn.z + En.w * Emn.w;
                float ai = En.y * Emn.x - En.x * Emn.y + En.w * Emn.z - En.z * Emn.w;

                // F[p] = A * Em[p]
                float fr0 = ar * Em.x - ai * Em.y, fi0 = ar * Em.y + ai * Em.x;
                float fr1 = ar * Em.z - ai * Em.w, fi1 = ar * Em.w + ai * Em.z;

                // acc[p][o] += F[p] * W1'[p][o][h]
                float wx, wy;
                wx = bf_lo(w.x); wy = bf_hi(w.x);
                a00r += fr0 * wx - fi0 * wy;  a00i += fr0 * wy + fi0 * wx;
                wx = bf_lo(w.y); wy = bf_hi(w.y);
                a01r += fr0 * wx - fi0 * wy;  a01i += fr0 * wy + fi0 * wx;
                wx = bf_lo(w.z); wy = bf_hi(w.z);
                a10r += fr1 * wx - fi1 * wy;  a10i += fr1 * wy + fi1 * wx;
                wx = bf_lo(w.w); wy = bf_hi(w.w);
                a11r += fr1 * wx - fi1 * wy;  a11i += fr1 * wy + fi1 * wx;
            }
            h += cnt; n += cnt;
        }
        ++mi;
        n = g_lay.n0[mi];
    }

    // ---- all x reads done; merge region aliases xsb ----
    __syncthreads();
    {
        float* P = reinterpret_cast<float*>(xsb) + wv * (8 * BPB);
        P[0*BPB+ln] = a00r; P[1*BPB+ln] = a00i;
        P[2*BPB+ln] = a01r; P[3*BPB+ln] = a01i;
        P[4*BPB+ln] = a10r; P[5*BPB+ln] = a10i;
        P[6*BPB+ln] = a11r; P[7*BPB+ln] = a11i;
    }
    __syncthreads();
    // ---- parallel merge: thread t owns 2 (k,lane) slots ----
    {
        float* P = reinterpret_cast<float*>(xsb);
        int k = t >> 6;
        #pragma unroll
        for (int kk = 0; kk < 2; ++kk) {
            int ks = k * 2 + kk;
            float s = P[0*(8*BPB) + ks*BPB + ln] + P[1*(8*BPB) + ks*BPB + ln]
                    + P[2*(8*BPB) + ks*BPB + ln] + P[3*(8*BPB) + ks*BPB + ln];
            P[NWAVE*(8*BPB) + ks*BPB + ln] = s;
        }
    }
    __syncthreads();

    // ---- MLP tail: one thread per batch elem ----
    if (t < BPB) {
        const float* accF = reinterpret_cast<const float*>(xsb) + NWAVE * (8 * BPB);
        float h1r[2][2], h1i[2][2];
        #pragma unroll
        for (int p = 0; p < 2; ++p)
            #pragma unroll
            for (int o = 0; o < 2; ++o) {
                h1r[p][o] = lrelu(accF[((p * 2 + o) * 2 + 0) * BPB + t]);
                h1i[p][o] = lrelu(accF[((p * 2 + o) * 2 + 1) * BPB + t]);
            }

        float Er[2], Ei[2];
        #pragma unroll
        for (int p = 0; p < 2; ++p) {
            float er = 0.f, ei = 0.f;
            #pragma unroll
            for (int q = 0; q < 10; ++q) {
                float hr = 0.f, hi = 0.f;
                #pragma unroll
                for (int o = 0; o < 2; ++o) {
                    float2 w = w2s[(p * 10 + q) * 2 + o];
                    hr += h1r[p][o] * w.x - h1i[p][o] * w.y;
                    hi += h1r[p][o] * w.y + h1i[p][o] * w.x;
                }
                hr = lrelu(hr); hi = lrelu(hi);
                float2 w3 = w3s[p * 10 + q];
                er += hr * w3.x - hi * w3.y;
                ei += hr * w3.y + hi * w3.x;
            }
            Er[p] = er; Ei[p] = ei;
        }

        int gb = b0 + t;
        float P = exp10f(task[gb * 4] * 0.1f) * 0.5f;   // 10^(ti/10) / NMODES

        // exact fp32 x[:,L,:] re-read from global (carrier term exact)
        const float* xrL = x_real + (size_t)gb * 82 + LHALF * 2;
        const float* xiL = x_imag + (size_t)gb * 82 + LHALF * 2;

        float4 o4;
        o4.x = xrL[0] + Er[0] * P;
        o4.y = xiL[0] + Ei[0] * P;
        o4.z = xrL[1] + Er[1] * P;
        o4.w = xiL[1] + Ei[1] * P;
        reinterpret_cast<float4*>(out)[gb] = o4;
    }
}

// ---------------- launch ----------------
extern "C" void kernel_launch(void* const* d_in, const int* in_sizes, int n_in,
                              void* d_out, int out_size, void* d_ws, size_t ws_size,
                              hipStream_t stream) {
    const float* x_real = (const float*)d_in[0];
    const float* x_imag = (const float*)d_in[1];
    const float* task   = (const float*)d_in[2];
    const float* W1r    = (const float*)d_in[3];
    const float* W1i    = (const float*)d_in[4];
    const float* W2r    = (const float*)d_in[5];
    const float* W2i    = (const float*)d_in[6];
    const float* W3r    = (const float*)d_in[7];
    const float* W3i    = (const float*)d_in[8];
    float* out = (float*)d_out;

    dim3 grid(BATCH / BPB);
    dim3 block(BLOCK);
    hipLaunchKernelGGL(eqpbcnn_kernel, grid, block, 0, stream,
                       x_real, x_imag, task, W1r, W1i, W2r, W2i, W3r, W3i, out);
}

// Round 10
// 34.394 us; speedup vs baseline: 7.7447x; 1.0019x over previous
//
#include <hip/hip_runtime.h>
#include <hip/hip_bf16.h>
#include <math.h>

// ---------------- problem constants ----------------
#define LHALF   20          // L = M//2, M = 41
#define HDIM    175         // number of (m,n) index pairs, verified below
#define BATCH   65536
#define SLOPE   0.01f

#define BPB     64          // batch elems per tile (= lanes per wave)
#define BLOCK   512         // 8 waves; waves split the h-range
#define NWAVE   8
#define HPW     22          // ceil(175/8)
#define TILES   2           // two tiles per block, software-pipelined
#define XROW    520         // bytes per i-row in LDS: 64 quads * 8B + 8B pad
#define F2PT    ((BPB * 41 + BLOCK - 1) / BLOCK)   // float2 loads per thread per tile (6)

// ---------------- compile-time layout ----------------
// Entries ordered m-major then n; for fixed m the admissible n-range is
// CONTIGUOUS, so the h-loop walks (m-group, n) and Em is group-invariant.
constexpr int count_idx() {
    int k = 0;
    for (int m = -LHALF; m <= LHALF; ++m)
        for (int n = m; n <= LHALF; ++n) {
            int mn = m * n; if (mn < 0) mn = -mn;
            int s  = m + n; if (s  < 0) s  = -s;
            if (mn <= LHALF && s <= LHALF) ++k;
        }
    return k;
}
static_assert(count_idx() == HDIM, "HDIM mismatch with reference enumeration");

struct Layout {
    int n0[42]; int n1[42];          // per mi (m = mi-20); n1<n0 => empty group
    int mi0[NWAVE]; int nf[NWAVE];   // per wave: starting group + starting n
    unsigned char sym2[HDIM];        // 1 if m != n
};

constexpr Layout make_layout() {
    Layout t{};
    for (int i = 0; i < 42; ++i) { t.n0[i] = 1; t.n1[i] = 0; }
    int h = 0;
    for (int m = -LHALF; m <= LHALF; ++m) {
        bool first = true;
        for (int n = m; n <= LHALF; ++n) {
            int mn = m * n; if (mn < 0) mn = -mn;
            int s  = m + n; if (s  < 0) s  = -s;
            if (mn <= LHALF && s <= LHALF) {
                int mi = m + LHALF;
                if (first) { t.n0[mi] = n; first = false; }
                t.n1[mi] = n;
                t.sym2[h] = (m != n) ? 1 : 0;
                for (int w = 0; w < NWAVE; ++w)
                    if (h == w * HPW) { t.mi0[w] = mi; t.nf[w] = n; }
                ++h;
            }
        }
    }
    return t;
}

__constant__ Layout g_lay = make_layout();

__device__ __forceinline__ float lrelu(float v) {
    return v > 0.0f ? v : SLOPE * v;
}

// bf16 quad (re0,im0,re1,im1) -> 4 floats
__device__ __forceinline__ float4 dec(uint2 q) {
    float4 r;
    r.x = __uint_as_float(q.x << 16);
    r.y = __uint_as_float(q.x & 0xffff0000u);
    r.z = __uint_as_float(q.y << 16);
    r.w = __uint_as_float(q.y & 0xffff0000u);
    return r;
}

// f32 -> bf16 (round-to-nearest-even)
__device__ __forceinline__ unsigned short f2bf(float f) {
    unsigned int u = __float_as_uint(f);
    u += 0x7fffu + ((u >> 16) & 1u);
    return (unsigned short)(u >> 16);
}

// ---- h-loop over one tile: m-group walk, Em hoisted out of inner loop ----
__device__ __forceinline__ void compute_tile(const char* __restrict__ xlane,
                                             const float4* __restrict__ pk4,
                                             int wv, float* __restrict__ a)
{
    #pragma unroll
    for (int k = 0; k < 8; ++k) a[k] = 0.f;

    int h          = wv * HPW;
    const int hend = (h + HPW < HDIM) ? h + HPW : HDIM;
    int mi = g_lay.mi0[wv];
    int n  = g_lay.nf[wv];

    while (h < hend) {
        int cnt = g_lay.n1[mi] - n + 1;
        int rem = hend - h;
        if (cnt > rem) cnt = rem;
        if (cnt > 0) {
            float g0 = 0.f, g1 = 0.f, g2 = 0.f, g3 = 0.f;
            float g4 = 0.f, g5 = 0.f, g6 = 0.f, g7 = 0.f;
            const char* pn  = xlane + (LHALF + n) * XROW;
            const char* pmn = xlane + (mi + n) * XROW;
            #pragma unroll 2
            for (int c = 0; c < cnt; ++c) {
                float4 wA = pk4[2 * (h + c)];        // broadcast b128
                float4 wB = pk4[2 * (h + c) + 1];
                float4 En  = dec(*reinterpret_cast<const uint2*>(pn  + c * XROW));
                float4 Emn = dec(*reinterpret_cast<const uint2*>(pmn + c * XROW));

                // A = sum over modes of En * conj(Emn)
                float ar = En.x * Emn.x + En.y * Emn.y + En.z * Emn.z + En.w * Emn.w;
                float ai = En.y * Emn.x - En.x * Emn.y + En.w * Emn.z - En.z * Emn.w;

                // gacc[p][o] += A * W1'[p][o][h]   (Em hoisted to group flush)
                g0 += ar * wA.x - ai * wA.y;  g1 += ar * wA.y + ai * wA.x;
                g2 += ar * wA.z - ai * wA.w;  g3 += ar * wA.w + ai * wA.z;
                g4 += ar * wB.x - ai * wB.y;  g5 += ar * wB.y + ai * wB.x;
                g6 += ar * wB.z - ai * wB.w;  g7 += ar * wB.w + ai * wB.z;
            }
            // flush: acc[p][o] += Em[p] * gacc[p][o]
            float4 Em = dec(*reinterpret_cast<const uint2*>(xlane + mi * XROW));
            a[0] += Em.x * g0 - Em.y * g1;  a[1] += Em.x * g1 + Em.y * g0;
            a[2] += Em.x * g2 - Em.y * g3;  a[3] += Em.x * g3 + Em.y * g2;
            a[4] += Em.z * g4 - Em.w * g5;  a[5] += Em.z * g5 + Em.w * g4;
            a[6] += Em.z * g6 - Em.w * g7;  a[7] += Em.z * g7 + Em.w * g6;
            h += cnt; n += cnt;
        }
        ++mi;
        n = g_lay.n0[mi];
    }
}

// ---------------- kernel ----------------
__global__ __launch_bounds__(BLOCK, 4) void eqpbcnn_kernel(
    const float* __restrict__ x_real, const float* __restrict__ x_imag,
    const float* __restrict__ task,
    const float* __restrict__ W1r, const float* __restrict__ W1i,
    const float* __restrict__ W2r, const float* __restrict__ W2i,
    const float* __restrict__ W3r, const float* __restrict__ W3i,
    float* __restrict__ out)
{
    __shared__ __align__(16) char   xsbA[41 * XROW];   // 21.3 KB tile A
    __shared__ __align__(16) char   xsbB[41 * XROW];   // 21.3 KB tile B
    __shared__ __align__(16) float4 pk4[HDIM * 2];     // 5.6 KB  W1'*sym f32
    __shared__ float mrg[NWAVE][8][BPB];               // 16 KB   per-wave partials
    __shared__ float2 w2s[2 * 10 * 2];
    __shared__ float2 w3s[2 * 10];

    const int t  = threadIdx.x;
    const int b0 = blockIdx.x * (BPB * TILES);
    const int ln = t & 63;
    const int wv = t >> 6;          // wave id 0..7

    // ---- stage tile A: coalesced float2 loads, bf16 quad writes ----
    {
        const float2* xr2 = reinterpret_cast<const float2*>(x_real) + (size_t)b0 * 41;
        const float2* xi2 = reinterpret_cast<const float2*>(x_imag) + (size_t)b0 * 41;
        #pragma unroll
        for (int k = 0; k < F2PT; ++k) {
            int f = t + k * BLOCK;
            if (f < BPB * 41) {
                float2 r2 = xr2[f];
                float2 i2 = xi2[f];
                int bl = f / 41;
                int i  = f - bl * 41;
                ushort4 q;
                q.x = f2bf(r2.x); q.y = f2bf(i2.x);
                q.z = f2bf(r2.y); q.w = f2bf(i2.y);
                *reinterpret_cast<ushort4*>(xsbA + i * XROW + bl * 8) = q;
            }
        }
    }
    // ---- build pk: W1 * sym, pre-decoded f32, 32 B per h ----
    if (t < HDIM) {
        float sym = g_lay.sym2[t] ? 2.0f : 1.0f;
        float4 wA, wB;
        wA.x = W1r[0 * HDIM + t] * sym;  wA.y = W1i[0 * HDIM + t] * sym;
        wA.z = W1r[1 * HDIM + t] * sym;  wA.w = W1i[1 * HDIM + t] * sym;
        wB.x = W1r[2 * HDIM + t] * sym;  wB.y = W1i[2 * HDIM + t] * sym;
        wB.z = W1r[3 * HDIM + t] * sym;  wB.w = W1i[3 * HDIM + t] * sym;
        pk4[2 * t]     = wA;
        pk4[2 * t + 1] = wB;
    }
    if (t >= 192 && t < 192 + 40)
        w2s[t - 192] = make_float2(W2r[t - 192], W2i[t - 192]);
    if (t >= 232 && t < 232 + 20)
        w3s[t - 232] = make_float2(W3r[t - 232], W3i[t - 232]);
    __syncthreads();

    // ---- issue tile B global loads into registers (hide under compute A) ----
    float2 rb[F2PT], ib[F2PT];
    {
        const float2* xr2 = reinterpret_cast<const float2*>(x_real) + (size_t)(b0 + BPB) * 41;
        const float2* xi2 = reinterpret_cast<const float2*>(x_imag) + (size_t)(b0 + BPB) * 41;
        #pragma unroll
        for (int k = 0; k < F2PT; ++k) {
            int f = t + k * BLOCK;
            if (f < BPB * 41) { rb[k] = xr2[f]; ib[k] = xi2[f]; }
        }
    }

    // ---- compute tile A ----
    {
        float a[8];
        compute_tile(xsbA + ln * 8, pk4, wv, a);
        #pragma unroll
        for (int k = 0; k < 8; ++k) mrg[wv][k][ln] = a[k];
    }

    // ---- drain tile B loads, pack, write to LDS (before the merge barrier) ----
    #pragma unroll
    for (int k = 0; k < F2PT; ++k) {
        int f = t + k * BLOCK;
        if (f < BPB * 41) {
            int bl = f / 41;
            int i  = f - bl * 41;
            ushort4 q;
            q.x = f2bf(rb[k].x); q.y = f2bf(ib[k].x);
            q.z = f2bf(rb[k].y); q.w = f2bf(ib[k].y);
            *reinterpret_cast<ushort4*>(xsbB + i * XROW + bl * 8) = q;
        }
    }
    __syncthreads();

    // ---- reduce A partials: thread t owns (k = t>>6, lane = t&63) ----
    {
        int k = t >> 6;
        float s = 0.f;
        #pragma unroll
        for (int w = 0; w < NWAVE; ++w) s += mrg[w][k][ln];
        mrg[0][k][ln] = s;
    }
    __syncthreads();

    // ---- tail A (wave 0) ; other waves fall through to compute B ----
    if (t < BPB) {
        float h1r[2][2], h1i[2][2];
        #pragma unroll
        for (int p = 0; p < 2; ++p)
            #pragma unroll
            for (int o = 0; o < 2; ++o) {
                h1r[p][o] = lrelu(mrg[0][(p * 2 + o) * 2 + 0][t]);
                h1i[p][o] = lrelu(mrg[0][(p * 2 + o) * 2 + 1][t]);
            }
        float Er[2], Ei[2];
        #pragma unroll
        for (int p = 0; p < 2; ++p) {
            float er = 0.f, ei = 0.f;
            #pragma unroll
            for (int q = 0; q < 10; ++q) {
                float hr = 0.f, hi = 0.f;
                #pragma unroll
                for (int o = 0; o < 2; ++o) {
                    float2 w = w2s[(p * 10 + q) * 2 + o];
                    hr += h1r[p][o] * w.x - h1i[p][o] * w.y;
                    hi += h1r[p][o] * w.y + h1i[p][o] * w.x;
                }
                hr = lrelu(hr); hi = lrelu(hi);
                float2 w3 = w3s[p * 10 + q];
                er += hr * w3.x - hi * w3.y;
                ei += hr * w3.y + hi * w3.x;
            }
            Er[p] = er; Ei[p] = ei;
        }
        int gb = b0 + t;
        float P = exp10f(task[gb * 4] * 0.1f) * 0.5f;
        const float* xrL = x_real + (size_t)gb * 82 + LHALF * 2;
        const float* xiL = x_imag + (size_t)gb * 82 + LHALF * 2;
        float4 o4;
        o4.x = xrL[0] + Er[0] * P;
        o4.y = xiL[0] + Ei[0] * P;
        o4.z = xrL[1] + Er[1] * P;
        o4.w = xiL[1] + Ei[1] * P;
        reinterpret_cast<float4*>(out)[gb] = o4;
    }

    // ---- compute tile B ----
    {
        float a[8];
        compute_tile(xsbB + ln * 8, pk4, wv, a);
        #pragma unroll
        for (int k = 0; k < 8; ++k) mrg[wv][k][ln] = a[k];
    }
    __syncthreads();

    // ---- reduce B partials ----
    {
        int k = t >> 6;
        float s = 0.f;
        #pragma unroll
        for (int w = 0; w < NWAVE; ++w) s += mrg[w][k][ln];
        mrg[0][k][ln] = s;
    }
    __syncthreads();

    // ---- tail B ----
    if (t < BPB) {
        float h1r[2][2], h1i[2][2];
        #pragma unroll
        for (int p = 0; p < 2; ++p)
            #pragma unroll
            for (int o = 0; o < 2; ++o) {
                h1r[p][o] = lrelu(mrg[0][(p * 2 + o) * 2 + 0][t]);
                h1i[p][o] = lrelu(mrg[0][(p * 2 + o) * 2 + 1][t]);
            }
        float Er[2], Ei[2];
        #pragma unroll
        for (int p = 0; p < 2; ++p) {
            float er = 0.f, ei = 0.f;
            #pragma unroll
            for (int q = 0; q < 10; ++q) {
                float hr = 0.f, hi = 0.f;
                #pragma unroll
                for (int o = 0; o < 2; ++o) {
                    float2 w = w2s[(p * 10 + q) * 2 + o];
                    hr += h1r[p][o] * w.x - h1i[p][o] * w.y;
                    hi += h1r[p][o] * w.y + h1i[p][o] * w.x;
                }
                hr = lrelu(hr); hi = lrelu(hi);
                float2 w3 = w3s[p * 10 + q];
                er += hr * w3.x - hi * w3.y;
                ei += hr * w3.y + hi * w3.x;
            }
            Er[p] = er; Ei[p] = ei;
        }
        int gb = b0 + BPB + t;
        float P = exp10f(task[gb * 4] * 0.1f) * 0.5f;
        const float* xrL = x_real + (size_t)gb * 82 + LHALF * 2;
        const float* xiL = x_imag + (size_t)gb * 82 + LHALF * 2;
        float4 o4;
        o4.x = xrL[0] + Er[0] * P;
        o4.y = xiL[0] + Ei[0] * P;
        o4.z = xrL[1] + Er[1] * P;
        o4.w = xiL[1] + Ei[1] * P;
        reinterpret_cast<float4*>(out)[gb] = o4;
    }
}

// ---------------- launch ----------------
extern "C" void kernel_launch(void* const* d_in, const int* in_sizes, int n_in,
                              void* d_out, int out_size, void* d_ws, size_t ws_size,
                              hipStream_t stream) {
    const float* x_real = (const float*)d_in[0];
    const float* x_imag = (const float*)d_in[1];
    const float* task   = (const float*)d_in[2];
    const float* W1r    = (const float*)d_in[3];
    const float* W1i    = (const float*)d_in[4];
    const float* W2r    = (const float*)d_in[5];
    const float* W2i    = (const float*)d_in[6];
    const float* W3r    = (const float*)d_in[7];
    const float* W3i    = (const float*)d_in[8];
    float* out = (float*)d_out;

    dim3 grid(BATCH / (BPB * TILES));   // 512 blocks, 2 per CU
    dim3 block(BLOCK);
    hipLaunchKernelGGL(eqpbcnn_kernel, grid, block, 0, stream,
                       x_real, x_imag, task, W1r, W1i, W2r, W2i, W3r, W3i, out);
}

// Round 12
// 26.414 us; speedup vs baseline: 10.0846x; 1.3021x over previous
//
#include <hip/hip_runtime.h>
#include <math.h>

// ---------------- problem constants ----------------
#define LHALF   20          // L = M//2, M = 41
#define HDIM    175         // number of (m,n) index pairs, verified below
#define BATCH   65536
#define SLOPE   0.01f

#define BPB     64          // batch elems per block (= lanes per wave)
#define BLOCK   256         // 4 waves; waves split the h-range
#define NWAVE   4
#define HCHUNK  44          // ceil(175/4)
#define XROW    520         // bytes per i-row in LDS: 64 quads * 8B + 8B pad

typedef _Float16 h2_t __attribute__((ext_vector_type(2)));

// ---------------- compile-time index table ----------------
constexpr int count_idx() {
    int k = 0;
    for (int m = -LHALF; m <= LHALF; ++m)
        for (int n = m; n <= LHALF; ++n) {
            int mn = m * n; if (mn < 0) mn = -mn;
            int s  = m + n; if (s  < 0) s  = -s;
            if (mn <= LHALF && s <= LHALF) ++k;
        }
    return k;
}
static_assert(count_idx() == HDIM, "HDIM mismatch with reference enumeration");

struct OffTab { int n[HDIM]; int mn[HDIM]; int m[HDIM]; unsigned char sym2[HDIM]; };

constexpr OffTab make_offtab() {
    OffTab t{};
    int k = 0;
    for (int m = -LHALF; m <= LHALF; ++m)
        for (int n = m; n <= LHALF; ++n) {
            int mn = m * n; if (mn < 0) mn = -mn;
            int s  = m + n; if (s  < 0) s  = -s;
            if (mn <= LHALF && s <= LHALF) {
                t.n[k]    = (LHALF + n)     * XROW;   // byte offsets into xs
                t.mn[k]   = (LHALF + m + n) * XROW;
                t.m[k]    = (LHALF + m)     * XROW;
                t.sym2[k] = (m != n) ? 1 : 0;
                ++k;
            }
        }
    return t;
}

__constant__ OffTab g_off = make_offtab();

__device__ __forceinline__ float lrelu(float v) {
    return v > 0.0f ? v : SLOPE * v;
}

// ---- f16 helpers (guarded builtins, scalar fallbacks) ----
__device__ __forceinline__ float fdot2u(unsigned int a, unsigned int b, float c) {
#if __has_builtin(__builtin_amdgcn_fdot2)
    return __builtin_amdgcn_fdot2(__builtin_bit_cast(h2_t, a),
                                  __builtin_bit_cast(h2_t, b), c, false);
#else
    h2_t ha = __builtin_bit_cast(h2_t, a), hb = __builtin_bit_cast(h2_t, b);
    return c + (float)ha[0] * (float)hb[0] + (float)ha[1] * (float)hb[1];
#endif
}
__device__ __forceinline__ unsigned int pk_h2(float a, float b) {
#if __has_builtin(__builtin_amdgcn_cvt_pkrtz)
    auto h = __builtin_amdgcn_cvt_pkrtz(a, b);   // __fp16 ext_vector_type(2)
    return __builtin_bit_cast(unsigned int, h);
#else
    h2_t h; h[0] = (_Float16)a; h[1] = (_Float16)b;
    return __builtin_bit_cast(unsigned int, h);
#endif
}
__device__ __forceinline__ float h_lo(unsigned int u) {
    return (float)__builtin_bit_cast(h2_t, u)[0];
}
__device__ __forceinline__ float h_hi(unsigned int u) {
    return (float)__builtin_bit_cast(h2_t, u)[1];
}
// (im, -re) helper for ai = dot2(en, swneg(emn))
__device__ __forceinline__ unsigned int swneg(unsigned int u) {
    return ((u >> 16) | (u << 16)) ^ 0x8000u;
}

// per-h packed row: f16 weight combos for dot2 accumulation + x offsets
struct __align__(16) PkRow {
    uint4 cA;   // p0: (wr00,-wi00),(wi00,wr00),(wr01,-wi01),(wi01,wr01)
    uint4 cB;   // p1: same for o0,o1
    int4  off;  // byte offsets: n, m+n, m, pad
};

// ---------------- kernel ----------------
__global__ __launch_bounds__(BLOCK, 4) void eqpbcnn_kernel(
    const float* __restrict__ x_real, const float* __restrict__ x_imag,
    const float* __restrict__ task,
    const float* __restrict__ W1r, const float* __restrict__ W1i,
    const float* __restrict__ W2r, const float* __restrict__ W2i,
    const float* __restrict__ W3r, const float* __restrict__ W3i,
    float* __restrict__ out)
{
    __shared__ __align__(16) char  xs[41 * XROW];      // 21.3 KB f16 quads (re0,im0,re1,im1)
    __shared__ __align__(16) PkRow pk[HDIM];           // 8.4 KB
    __shared__ float mrg[NWAVE][8][BPB];               // 8 KB per-wave partials
    __shared__ float2 w2s[2 * 10 * 2];
    __shared__ float2 w3s[2 * 10];

    const int t  = threadIdx.x;
    const int b0 = blockIdx.x * BPB;
    const int ln = t & 63;
    const int wv = t >> 6;          // wave id 0..3

    // ---- stage x: coalesced float2 loads; cvt_pkrtz f16 quad writes ----
    {
        const float2* xr2 = reinterpret_cast<const float2*>(x_real) + (size_t)b0 * 41;
        const float2* xi2 = reinterpret_cast<const float2*>(x_imag) + (size_t)b0 * 41;
        for (int f = t; f < BPB * 41; f += BLOCK) {
            float2 r2 = xr2[f];
            float2 i2 = xi2[f];
            int bl = f / 41;            // magic div
            int i  = f - bl * 41;
            uint2 q;
            q.x = pk_h2(r2.x, i2.x);    // mode0 (re, im)
            q.y = pk_h2(r2.y, i2.y);    // mode1 (re, im)
            *reinterpret_cast<uint2*>(xs + i * XROW + bl * 8) = q;
        }
    }
    // ---- build pk rows: f16 weight combos (sym folded) + offsets ----
    if (t < HDIM) {
        float sym = g_off.sym2[t] ? 2.0f : 1.0f;
        float wr0 = W1r[0 * HDIM + t] * sym, wi0 = W1i[0 * HDIM + t] * sym;
        float wr1 = W1r[1 * HDIM + t] * sym, wi1 = W1i[1 * HDIM + t] * sym;
        float wr2 = W1r[2 * HDIM + t] * sym, wi2 = W1i[2 * HDIM + t] * sym;
        float wr3 = W1r[3 * HDIM + t] * sym, wi3 = W1i[3 * HDIM + t] * sym;
        PkRow r;
        r.cA.x = pk_h2(wr0, -wi0);  r.cA.y = pk_h2(wi0, wr0);
        r.cA.z = pk_h2(wr1, -wi1);  r.cA.w = pk_h2(wi1, wr1);
        r.cB.x = pk_h2(wr2, -wi2);  r.cB.y = pk_h2(wi2, wr2);
        r.cB.z = pk_h2(wr3, -wi3);  r.cB.w = pk_h2(wi3, wr3);
        r.off  = make_int4(g_off.n[t], g_off.mn[t], g_off.m[t], 0);
        pk[t] = r;
    }
    if (t >= 192 && t < 192 + 40)
        w2s[t - 192] = make_float2(W2r[t - 192], W2i[t - 192]);
    if (t >= 232 && t < 232 + 20)
        w3s[t - 232] = make_float2(W3r[t - 232], W3i[t - 232]);
    __syncthreads();

    // ---- h-loop: wave-uniform h; dot2-based complex arithmetic ----
    float a[8] = {0.f, 0.f, 0.f, 0.f, 0.f, 0.f, 0.f, 0.f};
    const char* xlane = xs + ln * 8;
    const int hBeg = wv * HCHUNK;
    const int hEnd = (hBeg + HCHUNK < HDIM) ? hBeg + HCHUNK : HDIM;

    #pragma unroll 2
    for (int h = hBeg; h < hEnd; ++h) {
        const PkRow& r = pk[h];
        uint4 cA = r.cA;                                 // broadcast b128
        uint4 cB = r.cB;                                 // broadcast b128
        int4  of = r.off;                                // broadcast b128

        uint2 en  = *reinterpret_cast<const uint2*>(xlane + of.x);
        uint2 emn = *reinterpret_cast<const uint2*>(xlane + of.y);
        uint2 em  = *reinterpret_cast<const uint2*>(xlane + of.z);

        // A = sum over modes of En * conj(Emn)
        float ar = fdot2u(en.y, emn.y, fdot2u(en.x, emn.x, 0.f));
        float ai = fdot2u(en.y, swneg(emn.y), fdot2u(en.x, swneg(emn.x), 0.f));

        // F[p] = A * Em[p]  (f32)
        float emx = h_lo(em.x), emy = h_hi(em.x);
        float emz = h_lo(em.y), emw = h_hi(em.y);
        float fr0 = ar * emx - ai * emy, fi0 = ar * emy + ai * emx;
        float fr1 = ar * emz - ai * emw, fi1 = ar * emw + ai * emz;

        // pack F and accumulate via dot2 against weight combos
        unsigned int f0 = pk_h2(fr0, fi0);
        unsigned int f1 = pk_h2(fr1, fi1);
        a[0] = fdot2u(f0, cA.x, a[0]);  a[1] = fdot2u(f0, cA.y, a[1]);
        a[2] = fdot2u(f0, cA.z, a[2]);  a[3] = fdot2u(f0, cA.w, a[3]);
        a[4] = fdot2u(f1, cB.x, a[4]);  a[5] = fdot2u(f1, cB.y, a[5]);
        a[6] = fdot2u(f1, cB.z, a[6]);  a[7] = fdot2u(f1, cB.w, a[7]);
    }

    // ---- store per-wave partials ----
    #pragma unroll
    for (int k = 0; k < 8; ++k)
        mrg[wv][k][ln] = a[k];
    __syncthreads();

    // ---- parallel merge: thread t owns (k = t>>6 slots, lane = t&63) ----
    {
        int k = t >> 6;
        #pragma unroll
        for (int kk = 0; kk < 2; ++kk) {
            int ks = k * 2 + kk;
            float s = mrg[0][ks][ln] + mrg[1][ks][ln]
                    + mrg[2][ks][ln] + mrg[3][ks][ln];
            mrg[0][ks][ln] = s;
        }
    }
    __syncthreads();

    // ---- MLP tail: one thread per batch elem ----
    if (t < BPB) {
        float h1r[2][2], h1i[2][2];
        #pragma unroll
        for (int p = 0; p < 2; ++p)
            #pragma unroll
            for (int o = 0; o < 2; ++o) {
                h1r[p][o] = lrelu(mrg[0][(p * 2 + o) * 2 + 0][t]);
                h1i[p][o] = lrelu(mrg[0][(p * 2 + o) * 2 + 1][t]);
            }

        float Er[2], Ei[2];
        #pragma unroll
        for (int p = 0; p < 2; ++p) {
            float er = 0.f, ei = 0.f;
            #pragma unroll
            for (int q = 0; q < 10; ++q) {
                float hr = 0.f, hi = 0.f;
                #pragma unroll
                for (int o = 0; o < 2; ++o) {
                    float2 w = w2s[(p * 10 + q) * 2 + o];
                    hr += h1r[p][o] * w.x - h1i[p][o] * w.y;
                    hi += h1r[p][o] * w.y + h1i[p][o] * w.x;
                }
                hr = lrelu(hr); hi = lrelu(hi);
                float2 w3 = w3s[p * 10 + q];
                er += hr * w3.x - hi * w3.y;
                ei += hr * w3.y + hi * w3.x;
            }
            Er[p] = er; Ei[p] = ei;
        }

        int gb = b0 + t;
        float P = exp10f(task[gb * 4] * 0.1f) * 0.5f;   // 10^(ti/10) / NMODES

        // exact fp32 x[:,L,:] re-read from global (carrier term exact)
        const float* xrL = x_real + (size_t)gb * 82 + LHALF * 2;
        const float* xiL = x_imag + (size_t)gb * 82 + LHALF * 2;

        float4 o4;
        o4.x = xrL[0] + Er[0] * P;
        o4.y = xiL[0] + Ei[0] * P;
        o4.z = xrL[1] + Er[1] * P;
        o4.w = xiL[1] + Ei[1] * P;
        reinterpret_cast<float4*>(out)[gb] = o4;
    }
}

// ---------------- launch ----------------
extern "C" void kernel_launch(void* const* d_in, const int* in_sizes, int n_in,
                              void* d_out, int out_size, void* d_ws, size_t ws_size,
                              hipStream_t stream) {
    const float* x_real = (const float*)d_in[0];
    const float* x_imag = (const float*)d_in[1];
    const float* task   = (const float*)d_in[2];
    const float* W1r    = (const float*)d_in[3];
    const float* W1i    = (const float*)d_in[4];
    const float* W2r    = (const float*)d_in[5];
    const float* W2i    = (const float*)d_in[6];
    const float* W3r    = (const float*)d_in[7];
    const float* W3i    = (const float*)d_in[8];
    float* out = (float*)d_out;

    dim3 grid(BATCH / BPB);
    dim3 block(BLOCK);
    hipLaunchKernelGGL(eqpbcnn_kernel, grid, block, 0, stream,
                       x_real, x_imag, task, W1r, W1i, W2r, W2i, W3r, W3i, out);
}

// Round 13
// 24.654 us; speedup vs baseline: 10.8043x; 1.0714x over previous
//
#include <hip/hip_runtime.h>
#include <math.h>

// ---------------- problem constants ----------------
#define LHALF   20          // L = M//2, M = 41
#define HDIM    175         // number of (m,n) index pairs, verified below
#define BATCH   65536
#define SLOPE   0.01f

#define BPB     64          // batch elems per block (= lanes per wave)
#define BLOCK   256         // 4 waves; waves split the h-range
#define NWAVE   4
#define HCHUNK  44          // ceil(175/4)
#define XROW    520         // bytes per i-row in LDS: 64 quads * 8B + 8B pad
#define NGMAX   48          // >= number of non-empty m-groups (+1 dummy)

typedef _Float16 h2_t __attribute__((ext_vector_type(2)));

// ---------------- compile-time index table ----------------
constexpr int count_idx() {
    int k = 0;
    for (int m = -LHALF; m <= LHALF; ++m)
        for (int n = m; n <= LHALF; ++n) {
            int mn = m * n; if (mn < 0) mn = -mn;
            int s  = m + n; if (s  < 0) s  = -s;
            if (mn <= LHALF && s <= LHALF) ++k;
        }
    return k;
}
static_assert(count_idx() == HDIM, "HDIM mismatch with reference enumeration");

// m-groups: consecutive h runs sharing m (n contiguous within each run).
struct GrpTab {
    int endh[NGMAX];    // exclusive end h of group g
    int em  [NGMAX];    // byte offset of Em row (LHALF+m)
    int en0 [NGMAX];    // byte offset of En row at group start (LHALF+n0)
    int emn0[NGMAX];    // byte offset of Emn row at group start (LHALF+m+n0)
    int ng;
    unsigned char sym2[HDIM];
};

constexpr GrpTab make_grp() {
    GrpTab t{};
    int g = -1, h = 0, prev_m = -1000;
    for (int m = -LHALF; m <= LHALF; ++m)
        for (int n = m; n <= LHALF; ++n) {
            int mn = m * n; if (mn < 0) mn = -mn;
            int s  = m + n; if (s  < 0) s  = -s;
            if (mn <= LHALF && s <= LHALF) {
                if (m != prev_m) {
                    ++g;
                    t.em[g]   = (LHALF + m)     * XROW;
                    t.en0[g]  = (LHALF + n)     * XROW;
                    t.emn0[g] = (LHALF + m + n) * XROW;
                    prev_m = m;
                }
                t.endh[g] = h + 1;
                t.sym2[h] = (m != n) ? 1 : 0;
                ++h;
            }
        }
    t.ng = g + 1;
    // dummy tail entry (read after the last flush; must be valid offsets)
    t.endh[g + 1] = HDIM + 1000;
    t.em[g + 1] = 0; t.en0[g + 1] = 0; t.emn0[g + 1] = 0;
    return t;
}

constexpr GrpTab GT = make_grp();
static_assert(GT.ng + 1 <= NGMAX, "NGMAX too small");

// per-wave initial state at hBeg = wv*HCHUNK
struct WaveInit { int g; int endh; int em; int en; int emn; };

constexpr WaveInit winit_for(int hBeg) {
    WaveInit w{};
    int gs = 0;   // start h of group g
    for (int g = 0; g < GT.ng; ++g) {
        if (hBeg < GT.endh[g]) {
            w.g    = g;
            w.endh = GT.endh[g];
            w.em   = GT.em[g];
            w.en   = GT.en0[g]  + (hBeg - gs) * XROW;
            w.emn  = GT.emn0[g] + (hBeg - gs) * XROW;
            return w;
        }
        gs = GT.endh[g];
    }
    return w;
}

struct WInitArr { WaveInit w[NWAVE]; };
constexpr WInitArr make_winit() {
    WInitArr a{};
    for (int v = 0; v < NWAVE; ++v) a.w[v] = winit_for(v * HCHUNK);
    return a;
}
__constant__ WInitArr g_winit = make_winit();
__constant__ GrpTab   g_gt    = GT;

__device__ __forceinline__ float lrelu(float v) {
    return v > 0.0f ? v : SLOPE * v;
}

// ---- f16 helpers ----
__device__ __forceinline__ float fdot2u(unsigned int a, unsigned int b, float c) {
#if __has_builtin(__builtin_amdgcn_fdot2)
    return __builtin_amdgcn_fdot2(__builtin_bit_cast(h2_t, a),
                                  __builtin_bit_cast(h2_t, b), c, false);
#else
    h2_t ha = __builtin_bit_cast(h2_t, a), hb = __builtin_bit_cast(h2_t, b);
    return c + (float)ha[0] * (float)hb[0] + (float)ha[1] * (float)hb[1];
#endif
}
__device__ __forceinline__ unsigned int pk_h2(float a, float b) {
#if __has_builtin(__builtin_amdgcn_cvt_pkrtz)
    auto h = __builtin_amdgcn_cvt_pkrtz(a, b);   // __fp16 ext_vector_type(2)
    return __builtin_bit_cast(unsigned int, h);
#else
    h2_t h; h[0] = (_Float16)a; h[1] = (_Float16)b;
    return __builtin_bit_cast(unsigned int, h);
#endif
}
__device__ __forceinline__ float h_lo(unsigned int u) {
    return (float)__builtin_bit_cast(h2_t, u)[0];
}
__device__ __forceinline__ float h_hi(unsigned int u) {
    return (float)__builtin_bit_cast(h2_t, u)[1];
}
// (im, -re) for the conjugate cross term
__device__ __forceinline__ unsigned int swneg(unsigned int u) {
    return ((u >> 16) | (u << 16)) ^ 0x8000u;
}

// ---------------- kernel ----------------
__global__ __launch_bounds__(BLOCK, 4) void eqpbcnn_kernel(
    const float* __restrict__ x_real, const float* __restrict__ x_imag,
    const float* __restrict__ task,
    const float* __restrict__ W1r, const float* __restrict__ W1i,
    const float* __restrict__ W2r, const float* __restrict__ W2i,
    const float* __restrict__ W3r, const float* __restrict__ W3i,
    float* __restrict__ out)
{
    __shared__ __align__(16) char  xs[41 * XROW];      // 21.3 KB f16 quads
    __shared__ __align__(16) uint4 pk2[HDIM * 2];      // 5.6 KB weight combos (2 b128/h)
    __shared__ __align__(16) int4  grpT[NGMAX];        // 768 B group table
    __shared__ float mrg[NWAVE][8][BPB];               // 8 KB per-wave partials
    __shared__ float2 w2s[2 * 10 * 2];
    __shared__ float2 w3s[2 * 10];

    const int t  = threadIdx.x;
    const int b0 = blockIdx.x * BPB;
    const int ln = t & 63;
    const int wv = t >> 6;          // wave id 0..3

    // ---- stage x: coalesced float2 loads; f16 quad writes ----
    {
        const float2* xr2 = reinterpret_cast<const float2*>(x_real) + (size_t)b0 * 41;
        const float2* xi2 = reinterpret_cast<const float2*>(x_imag) + (size_t)b0 * 41;
        for (int f = t; f < BPB * 41; f += BLOCK) {
            float2 r2 = xr2[f];
            float2 i2 = xi2[f];
            int bl = f / 41;            // magic div
            int i  = f - bl * 41;
            uint2 q;
            q.x = pk_h2(r2.x, i2.x);    // mode0 (re, im)
            q.y = pk_h2(r2.y, i2.y);    // mode1 (re, im)
            *reinterpret_cast<uint2*>(xs + i * XROW + bl * 8) = q;
        }
    }
    // ---- build pk rows: f16 weight combos (sym folded), 32 B per h ----
    if (t < HDIM) {
        float sym = g_gt.sym2[t] ? 2.0f : 1.0f;
        float wr0 = W1r[0 * HDIM + t] * sym, wi0 = W1i[0 * HDIM + t] * sym;
        float wr1 = W1r[1 * HDIM + t] * sym, wi1 = W1i[1 * HDIM + t] * sym;
        float wr2 = W1r[2 * HDIM + t] * sym, wi2 = W1i[2 * HDIM + t] * sym;
        float wr3 = W1r[3 * HDIM + t] * sym, wi3 = W1i[3 * HDIM + t] * sym;
        uint4 cA, cB;
        cA.x = pk_h2(wr0, -wi0);  cA.y = pk_h2(wi0, wr0);
        cA.z = pk_h2(wr1, -wi1);  cA.w = pk_h2(wi1, wr1);
        cB.x = pk_h2(wr2, -wi2);  cB.y = pk_h2(wi2, wr2);
        cB.z = pk_h2(wr3, -wi3);  cB.w = pk_h2(wi3, wr3);
        pk2[2 * t]     = cA;
        pk2[2 * t + 1] = cB;
    }
    // ---- group table ----
    if (t >= 192 && t < 192 + NGMAX) {
        int g = t - 192;
        grpT[g] = make_int4(g_gt.endh[g], g_gt.em[g], g_gt.en0[g], g_gt.emn0[g]);
    }
    if (t >= 64 && t < 64 + 40)
        w2s[t - 64] = make_float2(W2r[t - 64], W2i[t - 64]);
    if (t >= 104 && t < 104 + 20)
        w3s[t - 104] = make_float2(W3r[t - 104], W3i[t - 104]);
    __syncthreads();

    // ---- h-loop: group-hoisted Em; pointer-incremented En/Emn ----
    float G[8] = {0.f, 0.f, 0.f, 0.f, 0.f, 0.f, 0.f, 0.f};
    float a[8] = {0.f, 0.f, 0.f, 0.f, 0.f, 0.f, 0.f, 0.f};
    const char* xlane = xs + ln * 8;

    WaveInit wi = g_winit.w[wv];
    int g      = wi.g;
    int endh   = wi.endh;
    int em_off = wi.em;
    const char* pn  = xlane + wi.en;
    const char* pmn = xlane + wi.emn;

    const int hBeg = wv * HCHUNK;
    const int hEnd = (hBeg + HCHUNK < HDIM) ? hBeg + HCHUNK : HDIM;

    for (int h = hBeg; h < hEnd; ++h) {
        uint4 cA = pk2[2 * h];                           // broadcast b128
        uint4 cB = pk2[2 * h + 1];                       // broadcast b128
        uint2 en  = *reinterpret_cast<const uint2*>(pn);   pn  += XROW;
        uint2 emn = *reinterpret_cast<const uint2*>(pmn);  pmn += XROW;

        // A = sum over modes of En * conj(Emn)
        float ar = fdot2u(en.y, emn.y, fdot2u(en.x, emn.x, 0.f));
        float ai = fdot2u(en.y, swneg(emn.y), fdot2u(en.x, swneg(emn.x), 0.f));
        unsigned int a2 = pk_h2(ar, ai);

        // G[p][o] += A * W1'[p][o][h]
        G[0] = fdot2u(a2, cA.x, G[0]);  G[1] = fdot2u(a2, cA.y, G[1]);
        G[2] = fdot2u(a2, cA.z, G[2]);  G[3] = fdot2u(a2, cA.w, G[3]);
        G[4] = fdot2u(a2, cB.x, G[4]);  G[5] = fdot2u(a2, cB.y, G[5]);
        G[6] = fdot2u(a2, cB.z, G[6]);  G[7] = fdot2u(a2, cB.w, G[7]);

        if (h + 1 == endh) {            // wave-uniform -> scalar branch
            // flush: acc[p][o] += Em[p] * G[p][o]
            uint2 em = *reinterpret_cast<const uint2*>(xlane + em_off);
            float er0 = h_lo(em.x), ei0 = h_hi(em.x);
            float er1 = h_lo(em.y), ei1 = h_hi(em.y);
            a[0] += er0 * G[0] - ei0 * G[1];  a[1] += er0 * G[1] + ei0 * G[0];
            a[2] += er0 * G[2] - ei0 * G[3];  a[3] += er0 * G[3] + ei0 * G[2];
            a[4] += er1 * G[4] - ei1 * G[5];  a[5] += er1 * G[5] + ei1 * G[4];
            a[6] += er1 * G[6] - ei1 * G[7];  a[7] += er1 * G[7] + ei1 * G[6];
            #pragma unroll
            for (int k = 0; k < 8; ++k) G[k] = 0.f;
            ++g;
            int4 e = grpT[g];
            endh = e.x; em_off = e.y;
            pn  = xlane + e.z;
            pmn = xlane + e.w;
        }
    }
    // final flush (adds 0 if the wave ended exactly on a group boundary)
    {
        uint2 em = *reinterpret_cast<const uint2*>(xlane + em_off);
        float er0 = h_lo(em.x), ei0 = h_hi(em.x);
        float er1 = h_lo(em.y), ei1 = h_hi(em.y);
        a[0] += er0 * G[0] - ei0 * G[1];  a[1] += er0 * G[1] + ei0 * G[0];
        a[2] += er0 * G[2] - ei0 * G[3];  a[3] += er0 * G[3] + ei0 * G[2];
        a[4] += er1 * G[4] - ei1 * G[5];  a[5] += er1 * G[5] + ei1 * G[4];
        a[6] += er1 * G[6] - ei1 * G[7];  a[7] += er1 * G[7] + ei1 * G[6];
    }

    // ---- store per-wave partials ----
    #pragma unroll
    for (int k = 0; k < 8; ++k)
        mrg[wv][k][ln] = a[k];
    __syncthreads();

    // ---- parallel merge: thread t owns 2 (k,lane) slots ----
    {
        int k = t >> 6;
        #pragma unroll
        for (int kk = 0; kk < 2; ++kk) {
            int ks = k * 2 + kk;
            float s = mrg[0][ks][ln] + mrg[1][ks][ln]
                    + mrg[2][ks][ln] + mrg[3][ks][ln];
            mrg[0][ks][ln] = s;
        }
    }
    __syncthreads();

    // ---- MLP tail: one thread per batch elem ----
    if (t < BPB) {
        float h1r[2][2], h1i[2][2];
        #pragma unroll
        for (int p = 0; p < 2; ++p)
            #pragma unroll
            for (int o = 0; o < 2; ++o) {
                h1r[p][o] = lrelu(mrg[0][(p * 2 + o) * 2 + 0][t]);
                h1i[p][o] = lrelu(mrg[0][(p * 2 + o) * 2 + 1][t]);
            }

        float Er[2], Ei[2];
        #pragma unroll
        for (int p = 0; p < 2; ++p) {
            float er = 0.f, ei = 0.f;
            #pragma unroll
            for (int q = 0; q < 10; ++q) {
                float hr = 0.f, hi = 0.f;
                #pragma unroll
                for (int o = 0; o < 2; ++o) {
                    float2 w = w2s[(p * 10 + q) * 2 + o];
                    hr += h1r[p][o] * w.x - h1i[p][o] * w.y;
                    hi += h1r[p][o] * w.y + h1i[p][o] * w.x;
                }
                hr = lrelu(hr); hi = lrelu(hi);
                float2 w3 = w3s[p * 10 + q];
                er += hr * w3.x - hi * w3.y;
                ei += hr * w3.y + hi * w3.x;
            }
            Er[p] = er; Ei[p] = ei;
        }

        int gb = b0 + t;
        float P = exp10f(task[gb * 4] * 0.1f) * 0.5f;   // 10^(ti/10) / NMODES

        // exact fp32 x[:,L,:] re-read from global (carrier term exact)
        const float* xrL = x_real + (size_t)gb * 82 + LHALF * 2;
        const float* xiL = x_imag + (size_t)gb * 82 + LHALF * 2;

        float4 o4;
        o4.x = xrL[0] + Er[0] * P;
        o4.y = xiL[0] + Ei[0] * P;
        o4.z = xrL[1] + Er[1] * P;
        o4.w = xiL[1] + Ei[1] * P;
        reinterpret_cast<float4*>(out)[gb] = o4;
    }
}

// ---------------- launch ----------------
extern "C" void kernel_launch(void* const* d_in, const int* in_sizes, int n_in,
                              void* d_out, int out_size, void* d_ws, size_t ws_size,
                              hipStream_t stream) {
    const float* x_real = (const float*)d_in[0];
    const float* x_imag = (const float*)d_in[1];
    const float* task   = (const float*)d_in[2];
    const float* W1r    = (const float*)d_in[3];
    const float* W1i    = (const float*)d_in[4];
    const float* W2r    = (const float*)d_in[5];
    const float* W2i    = (const float*)d_in[6];
    const float* W3r    = (const float*)d_in[7];
    const float* W3i    = (const float*)d_in[8];
    float* out = (float*)d_out;

    dim3 grid(BATCH / BPB);
    dim3 block(BLOCK);
    hipLaunchKernelGGL(eqpbcnn_kernel, grid, block, 0, stream,
                       x_real, x_imag, task, W1r, W1i, W2r, W2i, W3r, W3i, out);
}

// Round 14
// 23.431 us; speedup vs baseline: 11.3683x; 1.0522x over previous
//
#include <hip/hip_runtime.h>
#include <math.h>

// ---------------- problem constants ----------------
#define LHALF   20          // L = M//2, M = 41
#define HDIM    175         // number of (m,n) index pairs, verified below
#define BATCH   65536
#define SLOPE   0.01f

#define BPB     128         // batch elems per block (2 per lane)
#define BLOCK   512         // 8 waves; waves split the h-range
#define NWAVE   8
#define HPW     22          // ceil(175/8)
#define XROW    1040        // bytes per i-row: 128 quads * 8B + 16B pad
#define NGMAX   48          // >= number of non-empty m-groups (+1 dummy)

typedef _Float16 h2_t __attribute__((ext_vector_type(2)));

// ---------------- compile-time index table ----------------
constexpr int count_idx() {
    int k = 0;
    for (int m = -LHALF; m <= LHALF; ++m)
        for (int n = m; n <= LHALF; ++n) {
            int mn = m * n; if (mn < 0) mn = -mn;
            int s  = m + n; if (s  < 0) s  = -s;
            if (mn <= LHALF && s <= LHALF) ++k;
        }
    return k;
}
static_assert(count_idx() == HDIM, "HDIM mismatch with reference enumeration");

// m-groups: consecutive h runs sharing m (n contiguous within each run).
struct GrpTab {
    int endh[NGMAX];    // exclusive end h of group g
    int em  [NGMAX];    // byte offset of Em row (LHALF+m)
    int en0 [NGMAX];    // byte offset of En row at group start (LHALF+n0)
    int emn0[NGMAX];    // byte offset of Emn row at group start (LHALF+m+n0)
    int ng;
    unsigned char sym2[HDIM];
};

constexpr GrpTab make_grp() {
    GrpTab t{};
    int g = -1, h = 0, prev_m = -1000;
    for (int m = -LHALF; m <= LHALF; ++m)
        for (int n = m; n <= LHALF; ++n) {
            int mn = m * n; if (mn < 0) mn = -mn;
            int s  = m + n; if (s  < 0) s  = -s;
            if (mn <= LHALF && s <= LHALF) {
                if (m != prev_m) {
                    ++g;
                    t.em[g]   = (LHALF + m)     * XROW;
                    t.en0[g]  = (LHALF + n)     * XROW;
                    t.emn0[g] = (LHALF + m + n) * XROW;
                    prev_m = m;
                }
                t.endh[g] = h + 1;
                t.sym2[h] = (m != n) ? 1 : 0;
                ++h;
            }
        }
    t.ng = g + 1;
    // dummy tail entry (read after the last flush; must be valid offsets)
    t.endh[g + 1] = HDIM + 1000;
    t.em[g + 1] = 0; t.en0[g + 1] = 0; t.emn0[g + 1] = 0;
    return t;
}

constexpr GrpTab GT = make_grp();
static_assert(GT.ng + 1 <= NGMAX, "NGMAX too small");

// per-wave initial state at hBeg = wv*HPW
struct WaveInit { int g; int endh; int em; int en; int emn; };

constexpr WaveInit winit_for(int hBeg) {
    WaveInit w{};
    int gs = 0;   // start h of group g
    for (int g = 0; g < GT.ng; ++g) {
        if (hBeg < GT.endh[g]) {
            w.g    = g;
            w.endh = GT.endh[g];
            w.em   = GT.em[g];
            w.en   = GT.en0[g]  + (hBeg - gs) * XROW;
            w.emn  = GT.emn0[g] + (hBeg - gs) * XROW;
            return w;
        }
        gs = GT.endh[g];
    }
    return w;
}

struct WInitArr { WaveInit w[NWAVE]; };
constexpr WInitArr make_winit() {
    WInitArr a{};
    for (int v = 0; v < NWAVE; ++v) a.w[v] = winit_for(v * HPW);
    return a;
}
__constant__ WInitArr g_winit = make_winit();
__constant__ GrpTab   g_gt    = GT;

__device__ __forceinline__ float lrelu(float v) {
    return v > 0.0f ? v : SLOPE * v;
}

// ---- f16 helpers ----
__device__ __forceinline__ float fdot2u(unsigned int a, unsigned int b, float c) {
#if __has_builtin(__builtin_amdgcn_fdot2)
    return __builtin_amdgcn_fdot2(__builtin_bit_cast(h2_t, a),
                                  __builtin_bit_cast(h2_t, b), c, false);
#else
    h2_t ha = __builtin_bit_cast(h2_t, a), hb = __builtin_bit_cast(h2_t, b);
    return c + (float)ha[0] * (float)hb[0] + (float)ha[1] * (float)hb[1];
#endif
}
__device__ __forceinline__ unsigned int pk_h2(float a, float b) {
#if __has_builtin(__builtin_amdgcn_cvt_pkrtz)
    auto h = __builtin_amdgcn_cvt_pkrtz(a, b);   // __fp16 ext_vector_type(2)
    return __builtin_bit_cast(unsigned int, h);
#else
    h2_t h; h[0] = (_Float16)a; h[1] = (_Float16)b;
    return __builtin_bit_cast(unsigned int, h);
#endif
}
__device__ __forceinline__ float h_lo(unsigned int u) {
    return (float)__builtin_bit_cast(h2_t, u)[0];
}
__device__ __forceinline__ float h_hi(unsigned int u) {
    return (float)__builtin_bit_cast(h2_t, u)[1];
}
// (im, -re) for the conjugate cross term
__device__ __forceinline__ unsigned int swneg(unsigned int u) {
    return ((u >> 16) | (u << 16)) ^ 0x8000u;
}

// ---------------- kernel ----------------
__global__ __launch_bounds__(BLOCK, 4) void eqpbcnn_kernel(
    const float* __restrict__ x_real, const float* __restrict__ x_imag,
    const float* __restrict__ task,
    const float* __restrict__ W1r, const float* __restrict__ W1i,
    const float* __restrict__ W2r, const float* __restrict__ W2i,
    const float* __restrict__ W3r, const float* __restrict__ W3i,
    float* __restrict__ out)
{
    // x rows: 41 * 1040 B = 42.6 KB; after the h-loop this region is reused
    // for the merge buffer (8 waves * 8 k * 128 b * 4 B = 32 KB <= 42.6 KB).
    __shared__ __align__(16) char  xs[41 * XROW];
    __shared__ __align__(16) uint4 pk2[HDIM * 2];      // 5.6 KB weight combos
    __shared__ __align__(16) int4  grpT[NGMAX];        // 768 B group table
    __shared__ float2 w2s[2 * 10 * 2];
    __shared__ float2 w3s[2 * 10];

    static_assert(NWAVE * 8 * BPB * 4 <= 41 * XROW, "merge buffer must fit in xs");

    const int t  = threadIdx.x;
    const int b0 = blockIdx.x * BPB;
    const int ln = t & 63;
    const int wv = t >> 6;          // wave id 0..7

    // ---- stage x: coalesced float2 loads; f16 quad writes ----
    {
        const float2* xr2 = reinterpret_cast<const float2*>(x_real) + (size_t)b0 * 41;
        const float2* xi2 = reinterpret_cast<const float2*>(x_imag) + (size_t)b0 * 41;
        for (int f = t; f < BPB * 41; f += BLOCK) {
            float2 r2 = xr2[f];
            float2 i2 = xi2[f];
            int bl = f / 41;            // magic div
            int i  = f - bl * 41;
            uint2 q;
            q.x = pk_h2(r2.x, i2.x);    // mode0 (re, im)
            q.y = pk_h2(r2.y, i2.y);    // mode1 (re, im)
            *reinterpret_cast<uint2*>(xs + i * XROW + bl * 8) = q;
        }
    }
    // ---- build pk rows: f16 weight combos (sym folded), 32 B per h ----
    if (t < HDIM) {
        float sym = g_gt.sym2[t] ? 2.0f : 1.0f;
        float wr0 = W1r[0 * HDIM + t] * sym, wi0 = W1i[0 * HDIM + t] * sym;
        float wr1 = W1r[1 * HDIM + t] * sym, wi1 = W1i[1 * HDIM + t] * sym;
        float wr2 = W1r[2 * HDIM + t] * sym, wi2 = W1i[2 * HDIM + t] * sym;
        float wr3 = W1r[3 * HDIM + t] * sym, wi3 = W1i[3 * HDIM + t] * sym;
        uint4 cA, cB;
        cA.x = pk_h2(wr0, -wi0);  cA.y = pk_h2(wi0, wr0);
        cA.z = pk_h2(wr1, -wi1);  cA.w = pk_h2(wi1, wr1);
        cB.x = pk_h2(wr2, -wi2);  cB.y = pk_h2(wi2, wr2);
        cB.z = pk_h2(wr3, -wi3);  cB.w = pk_h2(wi3, wr3);
        pk2[2 * t]     = cA;
        pk2[2 * t + 1] = cB;
    }
    // ---- group table ----
    if (t >= 256 && t < 256 + NGMAX) {
        int g = t - 256;
        grpT[g] = make_int4(g_gt.endh[g], g_gt.em[g], g_gt.en0[g], g_gt.emn0[g]);
    }
    if (t >= 320 && t < 320 + 40)
        w2s[t - 320] = make_float2(W2r[t - 320], W2i[t - 320]);
    if (t >= 384 && t < 384 + 20)
        w3s[t - 384] = make_float2(W3r[t - 384], W3i[t - 384]);
    __syncthreads();

    // ---- h-loop: 2 batches per lane; group-hoisted Em; ptr-incremented rows ----
    float GA[8] = {0,0,0,0,0,0,0,0}, GB[8] = {0,0,0,0,0,0,0,0};
    float aA[8] = {0,0,0,0,0,0,0,0}, aB[8] = {0,0,0,0,0,0,0,0};
    const char* xlane = xs + ln * 16;       // batches 2ln, 2ln+1 adjacent

    WaveInit wi = g_winit.w[wv];
    int g      = wi.g;
    int endh   = wi.endh;
    int em_off = wi.em;
    const char* pn  = xlane + wi.en;
    const char* pmn = xlane + wi.emn;

    const int hBeg = wv * HPW;
    const int hEnd = (hBeg + HPW < HDIM) ? hBeg + HPW : HDIM;

    for (int h = hBeg; h < hEnd; ++h) {
        uint4 cA = pk2[2 * h];                           // broadcast b128
        uint4 cB = pk2[2 * h + 1];                       // broadcast b128
        uint4 en  = *reinterpret_cast<const uint4*>(pn);   pn  += XROW;
        uint4 emn = *reinterpret_cast<const uint4*>(pmn);  pmn += XROW;

        // A = sum over modes of En * conj(Emn), two batches in parallel
        float arA = fdot2u(en.y, emn.y, fdot2u(en.x, emn.x, 0.f));
        float aiA = fdot2u(en.y, swneg(emn.y), fdot2u(en.x, swneg(emn.x), 0.f));
        float arB = fdot2u(en.w, emn.w, fdot2u(en.z, emn.z, 0.f));
        float aiB = fdot2u(en.w, swneg(emn.w), fdot2u(en.z, swneg(emn.z), 0.f));
        unsigned int a2A = pk_h2(arA, aiA);
        unsigned int a2B = pk_h2(arB, aiB);

        // G[p][o] += A * W1'[p][o][h]
        GA[0] = fdot2u(a2A, cA.x, GA[0]);  GA[1] = fdot2u(a2A, cA.y, GA[1]);
        GA[2] = fdot2u(a2A, cA.z, GA[2]);  GA[3] = fdot2u(a2A, cA.w, GA[3]);
        GA[4] = fdot2u(a2A, cB.x, GA[4]);  GA[5] = fdot2u(a2A, cB.y, GA[5]);
        GA[6] = fdot2u(a2A, cB.z, GA[6]);  GA[7] = fdot2u(a2A, cB.w, GA[7]);
        GB[0] = fdot2u(a2B, cA.x, GB[0]);  GB[1] = fdot2u(a2B, cA.y, GB[1]);
        GB[2] = fdot2u(a2B, cA.z, GB[2]);  GB[3] = fdot2u(a2B, cA.w, GB[3]);
        GB[4] = fdot2u(a2B, cB.x, GB[4]);  GB[5] = fdot2u(a2B, cB.y, GB[5]);
        GB[6] = fdot2u(a2B, cB.z, GB[6]);  GB[7] = fdot2u(a2B, cB.w, GB[7]);

        if (h + 1 == endh) {            // wave-uniform -> scalar branch
            // flush: acc[p][o] += Em[p] * G[p][o]
            uint4 em = *reinterpret_cast<const uint4*>(xlane + em_off);
            float e0, e1;
            e0 = h_lo(em.x); e1 = h_hi(em.x);
            aA[0] += e0 * GA[0] - e1 * GA[1];  aA[1] += e0 * GA[1] + e1 * GA[0];
            aA[2] += e0 * GA[2] - e1 * GA[3];  aA[3] += e0 * GA[3] + e1 * GA[2];
            e0 = h_lo(em.y); e1 = h_hi(em.y);
            aA[4] += e0 * GA[4] - e1 * GA[5];  aA[5] += e0 * GA[5] + e1 * GA[4];
            aA[6] += e0 * GA[6] - e1 * GA[7];  aA[7] += e0 * GA[7] + e1 * GA[6];
            e0 = h_lo(em.z); e1 = h_hi(em.z);
            aB[0] += e0 * GB[0] - e1 * GB[1];  aB[1] += e0 * GB[1] + e1 * GB[0];
            aB[2] += e0 * GB[2] - e1 * GB[3];  aB[3] += e0 * GB[3] + e1 * GB[2];
            e0 = h_lo(em.w); e1 = h_hi(em.w);
            aB[4] += e0 * GB[4] - e1 * GB[5];  aB[5] += e0 * GB[5] + e1 * GB[4];
            aB[6] += e0 * GB[6] - e1 * GB[7];  aB[7] += e0 * GB[7] + e1 * GB[6];
            #pragma unroll
            for (int k = 0; k < 8; ++k) { GA[k] = 0.f; GB[k] = 0.f; }
            ++g;
            int4 e = grpT[g];
            endh = e.x; em_off = e.y;
            pn  = xlane + e.z;
            pmn = xlane + e.w;
        }
    }
    // final flush (adds 0 if the wave ended exactly on a group boundary)
    {
        uint4 em = *reinterpret_cast<const uint4*>(xlane + em_off);
        float e0, e1;
        e0 = h_lo(em.x); e1 = h_hi(em.x);
        aA[0] += e0 * GA[0] - e1 * GA[1];  aA[1] += e0 * GA[1] + e1 * GA[0];
        aA[2] += e0 * GA[2] - e1 * GA[3];  aA[3] += e0 * GA[3] + e1 * GA[2];
        e0 = h_lo(em.y); e1 = h_hi(em.y);
        aA[4] += e0 * GA[4] - e1 * GA[5];  aA[5] += e0 * GA[5] + e1 * GA[4];
        aA[6] += e0 * GA[6] - e1 * GA[7];  aA[7] += e0 * GA[7] + e1 * GA[6];
        e0 = h_lo(em.z); e1 = h_hi(em.z);
        aB[0] += e0 * GB[0] - e1 * GB[1];  aB[1] += e0 * GB[1] + e1 * GB[0];
        aB[2] += e0 * GB[2] - e1 * GB[3];  aB[3] += e0 * GB[3] + e1 * GB[2];
        e0 = h_lo(em.w); e1 = h_hi(em.w);
        aB[4] += e0 * GB[4] - e1 * GB[5];  aB[5] += e0 * GB[5] + e1 * GB[4];
        aB[6] += e0 * GB[6] - e1 * GB[7];  aB[7] += e0 * GB[7] + e1 * GB[6];
    }

    // ---- all x reads done; merge buffer aliases xs ----
    __syncthreads();
    {
        float* mrgF = reinterpret_cast<float*>(xs) + wv * (8 * BPB);
        #pragma unroll
        for (int k = 0; k < 8; ++k)
            *reinterpret_cast<float2*>(&mrgF[k * BPB + 2 * ln]) =
                make_float2(aA[k], aB[k]);
    }
    __syncthreads();
    // ---- parallel merge: 1024 slots over 512 threads (2 each) ----
    {
        float* mrgF = reinterpret_cast<float*>(xs);
        #pragma unroll
        for (int s = 0; s < 2; ++s) {
            int slot = t + s * BLOCK;       // slot = k*128 + b
            float sum = 0.f;
            #pragma unroll
            for (int w = 0; w < NWAVE; ++w)
                sum += mrgF[w * (8 * BPB) + slot];
            mrgF[slot] = sum;               // in-place region w=0
        }
    }
    __syncthreads();

    // ---- MLP tail: one thread per batch elem ----
    if (t < BPB) {
        const float* accF = reinterpret_cast<const float*>(xs);
        float h1r[2][2], h1i[2][2];
        #pragma unroll
        for (int p = 0; p < 2; ++p)
            #pragma unroll
            for (int o = 0; o < 2; ++o) {
                h1r[p][o] = lrelu(accF[((p * 2 + o) * 2 + 0) * BPB + t]);
                h1i[p][o] = lrelu(accF[((p * 2 + o) * 2 + 1) * BPB + t]);
            }

        float Er[2], Ei[2];
        #pragma unroll
        for (int p = 0; p < 2; ++p) {
            float er = 0.f, ei = 0.f;
            #pragma unroll
            for (int q = 0; q < 10; ++q) {
                float hr = 0.f, hi = 0.f;
                #pragma unroll
                for (int o = 0; o < 2; ++o) {
                    float2 w = w2s[(p * 10 + q) * 2 + o];
                    hr += h1r[p][o] * w.x - h1i[p][o] * w.y;
                    hi += h1r[p][o] * w.y + h1i[p][o] * w.x;
                }
                hr = lrelu(hr); hi = lrelu(hi);
                float2 w3 = w3s[p * 10 + q];
                er += hr * w3.x - hi * w3.y;
                ei += hr * w3.y + hi * w3.x;
            }
            Er[p] = er; Ei[p] = ei;
        }

        int gb = b0 + t;
        float P = exp10f(task[gb * 4] * 0.1f) * 0.5f;   // 10^(ti/10) / NMODES

        // exact fp32 x[:,L,:] re-read from global (carrier term exact)
        const float* xrL = x_real + (size_t)gb * 82 + LHALF * 2;
        const float* xiL = x_imag + (size_t)gb * 82 + LHALF * 2;

        float4 o4;
        o4.x = xrL[0] + Er[0] * P;
        o4.y = xiL[0] + Ei[0] * P;
        o4.z = xrL[1] + Er[1] * P;
        o4.w = xiL[1] + Ei[1] * P;
        reinterpret_cast<float4*>(out)[gb] = o4;
    }
}

// ---------------- launch ----------------
extern "C" void kernel_launch(void* const* d_in, const int* in_sizes, int n_in,
                              void* d_out, int out_size, void* d_ws, size_t ws_size,
                              hipStream_t stream) {
    const float* x_real = (const float*)d_in[0];
    const float* x_imag = (const float*)d_in[1];
    const float* task   = (const float*)d_in[2];
    const float* W1r    = (const float*)d_in[3];
    const float* W1i    = (const float*)d_in[4];
    const float* W2r    = (const float*)d_in[5];
    const float* W2i    = (const float*)d_in[6];
    const float* W3r    = (const float*)d_in[7];
    const float* W3i    = (const float*)d_in[8];
    float* out = (float*)d_out;

    dim3 grid(BATCH / BPB);     // 512 blocks
    dim3 block(BLOCK);
    hipLaunchKernelGGL(eqpbcnn_kernel, grid, block, 0, stream,
                       x_real, x_imag, task, W1r, W1i, W2r, W2i, W3r, W3i, out);
}